// Round 9
// baseline (502.655 us; speedup 1.0000x reference)
//
#include <hip/hip_runtime.h>
#include <math.h>

#define NN 100000      // nodes
#define CD 32          // classes / hidden
#define NPB 4          // nodes (waves) per block in fused layer kernel
#define LGRID 2048     // persistent layer blocks

#define SCAN_EPB 512                                   // counts per scan block
#define SCAN_NB  ((NN + SCAN_EPB - 1) / SCAN_EPB)      // 196 blocks

__device__ __forceinline__ float4 max4(float4 a, float4 b) {
    float4 r;
    r.x = fmaxf(a.x, b.x); r.y = fmaxf(a.y, b.y);
    r.z = fmaxf(a.z, b.z); r.w = fmaxf(a.w, b.w);
    return r;
}
__device__ __forceinline__ float2 max2(float2 a, float2 b) {
    float2 r; r.x = fmaxf(a.x, b.x); r.y = fmaxf(a.y, b.y); return r;
}

// ---------------------------------------------------------------------------
__global__ void detect_idx64(const void* edge, int* flag) {
    const long long* p = (const long long*)edge;
    int lane = threadIdx.x & 63;
    int bad = 0;
    for (int i = lane; i < 512; i += 64) {
        long long v = p[i];
        if (v < 0 || v >= NN) bad = 1;
    }
    unsigned long long anybad = __ballot(bad);
    if (lane == 0) *flag = (anybad == 0ULL) ? 1 : 0;
}

__device__ __forceinline__ int load_idx(const void* edge, int i, int is64) {
    if (is64) return (int)((const long long*)edge)[i];
    return ((const int*)edge)[i];
}

// ---------------------------------------------------------------------------
// CSR build (packed counters; cursor aliases counts).
__global__ void hist_kernel(const void* edge, int E, const int* flag,
                            int* __restrict__ counts) {
    const int is64 = *flag;
    int e = blockIdx.x * blockDim.x + threadIdx.x;
    if (e >= E) return;
    int dst = load_idx(edge, E + e, is64);
    atomicAdd(&counts[dst], 1);            // fire & forget
}

__global__ void scan_partial_kernel(const int* __restrict__ counts,
                                    int* __restrict__ blockSums) {
    __shared__ int red[256];
    const int b = blockIdx.x, t = threadIdx.x;
    const int base = b * SCAN_EPB + t * 2;
    int s = 0;
    if (base < NN)     s += counts[base];
    if (base + 1 < NN) s += counts[base + 1];
    red[t] = s;
    __syncthreads();
    for (int off = 128; off > 0; off >>= 1) {
        if (t < off) red[t] += red[t + off];
        __syncthreads();
    }
    if (t == 0) blockSums[b] = red[0];
}

__global__ void scan_bases_kernel(int* blockSums) {
    __shared__ int tmp[SCAN_NB];
    const int t = threadIdx.x;
    if (t < SCAN_NB) tmp[t] = blockSums[t];
    __syncthreads();
    if (t == 0) {
        int run = 0;
        for (int i = 0; i < SCAN_NB; ++i) { int c = tmp[i]; tmp[i] = run; run += c; }
    }
    __syncthreads();
    if (t < SCAN_NB) blockSums[t] = tmp[t];
}

__global__ void scan_final_kernel(const int* __restrict__ counts,
                                  const int* __restrict__ blockSums,
                                  int* __restrict__ offsets,
                                  int* __restrict__ cursor) {
    __shared__ int tsum[256];
    const int b = blockIdx.x, t = threadIdx.x;
    const int base = b * SCAN_EPB + t * 2;
    const int c0 = (base < NN)     ? counts[base]     : 0;
    const int c1 = (base + 1 < NN) ? counts[base + 1] : 0;
    tsum[t] = c0 + c1;
    __syncthreads();
    for (int off = 1; off < 256; off <<= 1) {
        int u = (t >= off) ? tsum[t - off] : 0;
        __syncthreads();
        tsum[t] += u;
        __syncthreads();
    }
    const int bbase = blockSums[b];
    const int excl  = tsum[t] - (c0 + c1);
    if (base < NN) {
        int o = bbase + excl;
        offsets[base] = o; cursor[base] = o;
        if (base + 1 < NN) {
            int o1 = o + c0;
            offsets[base + 1] = o1; cursor[base + 1] = o1;
        }
    }
    if (b == SCAN_NB - 1 && t == 255) offsets[NN] = bbase + tsum[255];  // == E
}

// 4 edges/thread straight-line: 4 independent atomicAdds in flight.
__global__ void fill_kernel(const void* edge, int E, const int* flag,
                            int* cursor, int* __restrict__ csr_src) {
    const int is64 = *flag;
    const int st   = blockDim.x;
    const int e0   = blockIdx.x * (st * 4) + threadIdx.x;
    const int e1 = e0 + st, e2 = e0 + 2 * st, e3 = e0 + 3 * st;
    const bool v0 = e0 < E, v1 = e1 < E, v2 = e2 < E, v3 = e3 < E;

    int s0 = 0, d0 = 0, s1 = 0, d1 = 0, s2 = 0, d2 = 0, s3 = 0, d3 = 0;
    if (v0) { s0 = load_idx(edge, e0, is64); d0 = load_idx(edge, E + e0, is64); }
    if (v1) { s1 = load_idx(edge, e1, is64); d1 = load_idx(edge, E + e1, is64); }
    if (v2) { s2 = load_idx(edge, e2, is64); d2 = load_idx(edge, E + e2, is64); }
    if (v3) { s3 = load_idx(edge, e3, is64); d3 = load_idx(edge, E + e3, is64); }

    int p0 = 0, p1 = 0, p2 = 0, p3 = 0;
    if (v0) p0 = atomicAdd(&cursor[d0], 1);
    if (v1) p1 = atomicAdd(&cursor[d1], 1);
    if (v2) p2 = atomicAdd(&cursor[d2], 1);
    if (v3) p3 = atomicAdd(&cursor[d3], 1);

    if (v0) csr_src[p0] = s0;
    if (v1) csr_src[p1] = s1;
    if (v2) csr_src[p2] = s2;
    if (v3) csr_src[p3] = s3;
}

// ---------------------------------------------------------------------------
// Fused SAGE layer, persistent blocks, barrier-free inner loop.
// __launch_bounds__(256,4): VGPR budget 128 so the per-lane weight columns
// (56 floats for DIN=50) stay RESIDENT (R8's 52-VGPR build proved the
// compiler re-loaded them from global inside the loop without this).
// Gather: float4 (DIN=32, 16 edges in flight) / float2 (DIN=50, 8 edges in
// flight). Dense: register weights, uniform ds_read_b128 for sAgg/sH, dual
// accumulators. MODE: 0 = relu, 2 = log_softmax.
template <int DIN, int MODE>
__global__ __launch_bounds__(256, 4)
void sage_layer_kernel(const float* __restrict__ h,
                       const int* __restrict__ offsets,
                       const int* __restrict__ csr_src,
                       const float* __restrict__ Wl,
                       const float* __restrict__ bl,
                       const float* __restrict__ Wr,
                       float* __restrict__ out) {
    constexpr int KH = (DIN == 32) ? 16 : 28;   // k-range per wave half
    constexpr int ST = (DIN == 32) ? 32 : 56;   // LDS row stride (floats)

    __shared__ __align__(16) float sAgg[NPB][ST];
    __shared__ __align__(16) float sH[NPB][ST];

    const int tid  = threadIdx.x;
    const int g    = tid >> 6;          // wave id = local node slot
    const int lane = tid & 63;
    const int p    = lane >> 5;         // wave half
    const int j    = lane & 31;         // output column
    const int k0   = p * KH;

    // Per-lane weight columns in registers (zero-padded past DIN).
    float rWl[KH], rWr[KH];
#pragma unroll
    for (int kk = 0; kk < KH; ++kk) {
        const int k = k0 + kk;
        const bool v = (k < DIN);
        rWl[kk] = v ? Wl[k * CD + j] : 0.0f;
        rWr[kk] = v ? Wr[k * CD + j] : 0.0f;
    }
    const float rB = bl[j];

    // Zero the LDS pad (k in [DIN, 2*KH)) once; never overwritten below.
    if (DIN == 50 && p == 1 && j < 3) {
        sAgg[g][50 + 2 * j] = 0.0f; sAgg[g][51 + 2 * j] = 0.0f;
        sH[g][50 + 2 * j]   = 0.0f; sH[g][51 + 2 * j]   = 0.0f;
    }

    const float NEG = -INFINITY;
    const int ngrp = (NN + NPB - 1) / NPB;

    for (int grp = blockIdx.x; grp < ngrp; grp += gridDim.x) {
        const int n = grp * NPB + g;
        if (n < NN) {
            const int beg = offsets[n];
            const int end = offsets[n + 1];
            if (DIN == 32) {
                // lane = e*8 + c : 8 edges × 8 float4 chunks; unroll x2.
                const int e = lane >> 3;
                const int c = lane & 7;
                float4 A0 = {NEG, NEG, NEG, NEG};
                float4 A1 = {NEG, NEG, NEG, NEG};
                int i = beg;
                for (; i + 16 <= end; i += 16) {
                    int s0 = csr_src[i + e];
                    int s1 = csr_src[i + 8 + e];
                    A0 = max4(A0, *(const float4*)&h[(size_t)s0 * 32 + c * 4]);
                    A1 = max4(A1, *(const float4*)&h[(size_t)s1 * 32 + c * 4]);
                }
                if (i + e < end) {
                    int s0 = csr_src[i + e];
                    A0 = max4(A0, *(const float4*)&h[(size_t)s0 * 32 + c * 4]);
                }
                if (i + 8 + e < end) {
                    int s1 = csr_src[i + 8 + e];
                    A1 = max4(A1, *(const float4*)&h[(size_t)s1 * 32 + c * 4]);
                }
                A0 = max4(A0, A1);
                #pragma unroll
                for (int off = 8; off <= 32; off <<= 1) {
                    float4 t;
                    t.x = __shfl_xor(A0.x, off); t.y = __shfl_xor(A0.y, off);
                    t.z = __shfl_xor(A0.z, off); t.w = __shfl_xor(A0.w, off);
                    A0 = max4(A0, t);
                }
                A0.x = (A0.x == NEG) ? 0.0f : A0.x;
                A0.y = (A0.y == NEG) ? 0.0f : A0.y;
                A0.z = (A0.z == NEG) ? 0.0f : A0.z;
                A0.w = (A0.w == NEG) ? 0.0f : A0.w;
                if (lane < 8) {
                    *(float4*)&sAgg[g][lane * 4] = A0;
                } else if (lane < 16) {
                    const int c2 = lane - 8;
                    float4 own = *(const float4*)&h[(size_t)n * 32 + c2 * 4];
                    *(float4*)&sH[g][c2 * 4] = own;
                }
            } else {
                // halves = 2 edges, float2 chunks c<25, unroll x8 (8 edges in
                // flight per wave — R8's x4 halved MLP vs R7 and regressed).
                const int c = j;
                const bool ac = (c < 25);
                float2 A[8];
#pragma unroll
                for (int kk = 0; kk < 8; ++kk) A[kk] = make_float2(NEG, NEG);
                int i = beg + p;
                for (; i + 14 < end; i += 16) {
                    int s[8];
#pragma unroll
                    for (int kk = 0; kk < 8; ++kk) s[kk] = csr_src[i + 2 * kk];
                    if (ac) {
#pragma unroll
                        for (int kk = 0; kk < 8; ++kk)
                            A[kk] = max2(A[kk], *(const float2*)&h[(size_t)s[kk] * 50 + 2 * c]);
                    }
                }
                if (ac) {
#pragma unroll
                    for (int kk = 0; kk < 7; ++kk) {
                        if (i + 2 * kk < end)
                            A[kk] = max2(A[kk], *(const float2*)&h[(size_t)csr_src[i + 2 * kk] * 50 + 2 * c]);
                    }
                }
#pragma unroll
                for (int off2 = 4; off2 > 0; off2 >>= 1)
#pragma unroll
                    for (int kk = 0; kk < off2; ++kk) A[kk] = max2(A[kk], A[kk + off2]);
                float2 A0 = A[0];
                A0.x = fmaxf(A0.x, __shfl_xor(A0.x, 32));
                A0.y = fmaxf(A0.y, __shfl_xor(A0.y, 32));
                A0.x = (A0.x == NEG) ? 0.0f : A0.x;
                A0.y = (A0.y == NEG) ? 0.0f : A0.y;
                if (p == 0 && ac) {
                    *(float2*)&sAgg[g][2 * c] = A0;
                } else if (p == 1 && ac) {
                    float2 own = *(const float2*)&h[(size_t)n * 50 + 2 * c];
                    *(float2*)&sH[g][2 * c] = own;
                }
            }
        }
        // no barrier: same-wave LDS write -> read (compiler orders via lgkmcnt)

        if (n < NN) {
            float part0 = (p == 0) ? rB : 0.0f;
            float part1 = 0.0f;
#pragma unroll
            for (int it = 0; it < KH / 4; ++it) {
                float4 a  = *(const float4*)&sAgg[g][k0 + it * 4];
                float4 hh = *(const float4*)&sH[g][k0 + it * 4];
                part0 += a.x  * rWl[it * 4]     + a.y  * rWl[it * 4 + 1]
                       + a.z  * rWl[it * 4 + 2] + a.w  * rWl[it * 4 + 3];
                part1 += hh.x * rWr[it * 4]     + hh.y * rWr[it * 4 + 1]
                       + hh.z * rWr[it * 4 + 2] + hh.w * rWr[it * 4 + 3];
            }
            float part = part0 + part1;
            float acc = part + __shfl_xor(part, 32);
            if (lane < 32) {
                if (MODE == 0) acc = fmaxf(acc, 0.0f);
                if (MODE == 2) {
                    float m = acc;
                    for (int off = 16; off > 0; off >>= 1) m = fmaxf(m, __shfl_xor(m, off, 32));
                    float ex = expf(acc - m);
                    float s = ex;
                    for (int off = 16; off > 0; off >>= 1) s += __shfl_xor(s, off, 32);
                    acc = acc - m - logf(s);
                }
                out[(size_t)n * CD + j] = acc;
            }
        }
    }
}

// ---------------------------------------------------------------------------
extern "C" void kernel_launch(void* const* d_in, const int* in_sizes, int n_in,
                              void* d_out, int out_size, void* d_ws, size_t ws_size,
                              hipStream_t stream) {
    const float* x    = (const float*)d_in[0];
    const void*  edge = d_in[1];
    const float* Wl1 = (const float*)d_in[2];
    const float* bl1 = (const float*)d_in[3];
    const float* Wr1 = (const float*)d_in[4];
    const float* Wl2 = (const float*)d_in[5];
    const float* bl2 = (const float*)d_in[6];
    const float* Wr2 = (const float*)d_in[7];
    const float* Wl3 = (const float*)d_in[8];
    const float* bl3 = (const float*)d_in[9];
    const float* Wr3 = (const float*)d_in[10];

    const int E = in_sizes[1] / 2;

    // Workspace carve-up (256B aligned). Total ≈ 32.8 MB.
    char* ws = (char*)d_ws;
    size_t off = 0;
    auto carve = [&](size_t bytes) {
        void* p = ws + off;
        off = (off + bytes + 255) & ~(size_t)255;
        return p;
    };
    int*   counts    = (int*)  carve((size_t)NN * 4);       // aliased as cursor
    int*   cursor    = counts;
    int*   offsets   = (int*)  carve((size_t)(NN + 1) * 4);
    int*   flag      = (int*)  carve(4);
    int*   blockSums = (int*)  carve((size_t)SCAN_NB * 4);
    int*   csr_src   = (int*)  carve((size_t)E * 4);
    float* h1        = (float*)carve((size_t)NN * CD * 4);
    float* h2        = (float*)carve((size_t)NN * CD * 4);
    float* out       = (float*)d_out;
    (void)ws_size; (void)n_in; (void)out_size;

    hipMemsetAsync(counts, 0, (size_t)NN * 4, stream);
    detect_idx64<<<1, 64, 0, stream>>>(edge, flag);

    const int eb1 = (E + 255) / 256;
    const int eb4 = (E + 1023) / 1024;
    hist_kernel<<<eb1, 256, 0, stream>>>(edge, E, flag, counts);
    scan_partial_kernel<<<SCAN_NB, 256, 0, stream>>>(counts, blockSums);
    scan_bases_kernel<<<1, 256, 0, stream>>>(blockSums);
    scan_final_kernel<<<SCAN_NB, 256, 0, stream>>>(counts, blockSums, offsets, cursor);
    fill_kernel<<<eb4, 256, 0, stream>>>(edge, E, flag, cursor, csr_src);

    sage_layer_kernel<50, 0><<<LGRID, 256, 0, stream>>>(x,  offsets, csr_src, Wl1, bl1, Wr1, h1);
    sage_layer_kernel<32, 0><<<LGRID, 256, 0, stream>>>(h1, offsets, csr_src, Wl2, bl2, Wr2, h2);
    sage_layer_kernel<32, 2><<<LGRID, 256, 0, stream>>>(h2, offsets, csr_src, Wl3, bl3, Wr3, out);
}

// Round 10
// 460.915 us; speedup vs baseline: 1.0906x; 1.0906x over previous
//
#include <hip/hip_runtime.h>
#include <math.h>

#define NN 100000      // nodes
#define CD 32          // classes / hidden
#define NPB 4          // nodes (waves) per block in fused layer kernel
#define LGRID 2048     // persistent layer blocks

#define SCAN_EPB 512                                   // counts per scan block
#define SCAN_NB  ((NN + SCAN_EPB - 1) / SCAN_EPB)      // 196 blocks

typedef unsigned int  uint32;
typedef unsigned short ushort16;

// fp32 -> bf16 round-to-nearest-even (manual, no API dependency)
__device__ __forceinline__ ushort16 f2b(float f) {
    uint32 u = __float_as_uint(f);
    u = (u + 0x7FFFu + ((u >> 16) & 1u)) >> 16;
    return (ushort16)u;
}
// packed bf16 pair -> two fp32 (bit shifts only, exact)
__device__ __forceinline__ float b2f_lo(uint32 u) { return __uint_as_float(u << 16); }
__device__ __forceinline__ float b2f_hi(uint32 u) { return __uint_as_float(u & 0xFFFF0000u); }

// ---------------------------------------------------------------------------
__global__ void detect_idx64(const void* edge, int* flag) {
    const long long* p = (const long long*)edge;
    int lane = threadIdx.x & 63;
    int bad = 0;
    for (int i = lane; i < 512; i += 64) {
        long long v = p[i];
        if (v < 0 || v >= NN) bad = 1;
    }
    unsigned long long anybad = __ballot(bad);
    if (lane == 0) *flag = (anybad == 0ULL) ? 1 : 0;
}

__device__ __forceinline__ int load_idx(const void* edge, int i, int is64) {
    if (is64) return (int)((const long long*)edge)[i];
    return ((const int*)edge)[i];
}

// ---------------------------------------------------------------------------
// x (fp32, NN*50) -> packed bf16 pairs (uint32, NN*25). 4 floats/thread.
__global__ void cvt_x_kernel(const float* __restrict__ x, uint32* __restrict__ xb) {
    const int t = blockIdx.x * blockDim.x + threadIdx.x;   // uint2 index
    const int NQ = NN * 50 / 4;                             // 1,250,000
    if (t >= NQ) return;
    float4 v = *(const float4*)&x[t * 4];
    uint2 o;
    o.x = (uint32)f2b(v.x) | ((uint32)f2b(v.y) << 16);
    o.y = (uint32)f2b(v.z) | ((uint32)f2b(v.w) << 16);
    *(uint2*)&xb[t * 2] = o;
}

// ---------------------------------------------------------------------------
// CSR build (packed counters; cursor aliases counts).
__global__ void hist_kernel(const void* edge, int E, const int* flag,
                            int* __restrict__ counts) {
    const int is64 = *flag;
    int e = blockIdx.x * blockDim.x + threadIdx.x;
    if (e >= E) return;
    int dst = load_idx(edge, E + e, is64);
    atomicAdd(&counts[dst], 1);            // fire & forget
}

__global__ void scan_partial_kernel(const int* __restrict__ counts,
                                    int* __restrict__ blockSums) {
    __shared__ int red[256];
    const int b = blockIdx.x, t = threadIdx.x;
    const int base = b * SCAN_EPB + t * 2;
    int s = 0;
    if (base < NN)     s += counts[base];
    if (base + 1 < NN) s += counts[base + 1];
    red[t] = s;
    __syncthreads();
    for (int off = 128; off > 0; off >>= 1) {
        if (t < off) red[t] += red[t + off];
        __syncthreads();
    }
    if (t == 0) blockSums[b] = red[0];
}

__global__ void scan_bases_kernel(int* blockSums) {
    __shared__ int tmp[SCAN_NB];
    const int t = threadIdx.x;
    if (t < SCAN_NB) tmp[t] = blockSums[t];
    __syncthreads();
    if (t == 0) {
        int run = 0;
        for (int i = 0; i < SCAN_NB; ++i) { int c = tmp[i]; tmp[i] = run; run += c; }
    }
    __syncthreads();
    if (t < SCAN_NB) blockSums[t] = tmp[t];
}

__global__ void scan_final_kernel(const int* __restrict__ counts,
                                  const int* __restrict__ blockSums,
                                  int* __restrict__ offsets,
                                  int* __restrict__ cursor) {
    __shared__ int tsum[256];
    const int b = blockIdx.x, t = threadIdx.x;
    const int base = b * SCAN_EPB + t * 2;
    const int c0 = (base < NN)     ? counts[base]     : 0;
    const int c1 = (base + 1 < NN) ? counts[base + 1] : 0;
    tsum[t] = c0 + c1;
    __syncthreads();
    for (int off = 1; off < 256; off <<= 1) {
        int u = (t >= off) ? tsum[t - off] : 0;
        __syncthreads();
        tsum[t] += u;
        __syncthreads();
    }
    const int bbase = blockSums[b];
    const int excl  = tsum[t] - (c0 + c1);
    if (base < NN) {
        int o = bbase + excl;
        offsets[base] = o; cursor[base] = o;
        if (base + 1 < NN) {
            int o1 = o + c0;
            offsets[base + 1] = o1; cursor[base + 1] = o1;
        }
    }
    if (b == SCAN_NB - 1 && t == 255) offsets[NN] = bbase + tsum[255];  // == E
}

// 4 edges/thread straight-line: 4 independent atomicAdds in flight.
__global__ void fill_kernel(const void* edge, int E, const int* flag,
                            int* cursor, int* __restrict__ csr_src) {
    const int is64 = *flag;
    const int st   = blockDim.x;
    const int e0   = blockIdx.x * (st * 4) + threadIdx.x;
    const int e1 = e0 + st, e2 = e0 + 2 * st, e3 = e0 + 3 * st;
    const bool v0 = e0 < E, v1 = e1 < E, v2 = e2 < E, v3 = e3 < E;

    int s0 = 0, d0 = 0, s1 = 0, d1 = 0, s2 = 0, d2 = 0, s3 = 0, d3 = 0;
    if (v0) { s0 = load_idx(edge, e0, is64); d0 = load_idx(edge, E + e0, is64); }
    if (v1) { s1 = load_idx(edge, e1, is64); d1 = load_idx(edge, E + e1, is64); }
    if (v2) { s2 = load_idx(edge, e2, is64); d2 = load_idx(edge, E + e2, is64); }
    if (v3) { s3 = load_idx(edge, e3, is64); d3 = load_idx(edge, E + e3, is64); }

    int p0 = 0, p1 = 0, p2 = 0, p3 = 0;
    if (v0) p0 = atomicAdd(&cursor[d0], 1);
    if (v1) p1 = atomicAdd(&cursor[d1], 1);
    if (v2) p2 = atomicAdd(&cursor[d2], 1);
    if (v3) p3 = atomicAdd(&cursor[d3], 1);

    if (v0) csr_src[p0] = s0;
    if (v1) csr_src[p1] = s1;
    if (v2) csr_src[p2] = s2;
    if (v3) csr_src[p3] = s3;
}

// ---------------------------------------------------------------------------
// Fused SAGE layer — R7 structure (best measured: LDS weights, low VGPR, high
// occupancy), with BF16 node features: h rows are packed bf16 pairs (uint32),
// halving gather bytes (layer1 200->100 B/edge, layers2/3 128->64 B = 1 line).
// Gather: 2 edges/wave (halves) x unroll4 = 8 loads in flight, 4B each,
// unpacked by shift/and (exact). Dense: fp32 weights in LDS, k split across
// halves (R7). MODE: 0 = relu -> bf16 out, 2 = log_softmax -> fp32 out.
// DIN=50: row stride 25 uints; DIN=32: 16 uints.
template <int DIN, int MODE>
__global__ void sage_layer_kernel(const uint32* __restrict__ hb,
                                  const int* __restrict__ offsets,
                                  const int* __restrict__ csr_src,
                                  const float* __restrict__ Wl,
                                  const float* __restrict__ bl,
                                  const float* __restrict__ Wr,
                                  void* __restrict__ out_v) {
    constexpr int CW = DIN / 2;          // uint chunks per row (25 or 16)
    constexpr int ST = (DIN == 32) ? 32 : 56;   // LDS row stride (floats)

    __shared__ float sWl[DIN * CD];
    __shared__ float sWr[DIN * CD];
    __shared__ float sb[CD];
    __shared__ __align__(8) float sAgg[NPB][ST];
    __shared__ __align__(8) float sH[NPB][ST];

    const int tid = threadIdx.x;
    for (int i = tid; i < DIN * CD; i += blockDim.x) {
        sWl[i] = Wl[i];
        sWr[i] = Wr[i];
    }
    if (tid < CD) sb[tid] = bl[tid];
    __syncthreads();                      // the ONLY barrier in this kernel

    const int g    = tid >> 6;            // wave id = local node slot
    const int lane = tid & 63;
    const int p    = lane >> 5;           // wave half
    const int j    = lane & 31;
    const bool ac  = (j < CW);            // active chunk lanes

    const float NEG = -INFINITY;
    const int ngrp = (NN + NPB - 1) / NPB;

    for (int grp = blockIdx.x; grp < ngrp; grp += gridDim.x) {
        const int n = grp * NPB + g;
        if (n < NN) {
            const int beg = offsets[n];
            const int end = offsets[n + 1];
            // 2 edges per wave (halves) x unroll4 -> 8 independent loads.
            float l0 = NEG, h0 = NEG, l1 = NEG, h1 = NEG;
            float l2 = NEG, h2 = NEG, l3 = NEG, h3 = NEG;
            int i = beg + p;
            for (; i + 6 < end; i += 8) {
                int s0 = csr_src[i];
                int s1 = csr_src[i + 2];
                int s2 = csr_src[i + 4];
                int s3 = csr_src[i + 6];
                if (ac) {
                    uint32 u0 = hb[(size_t)s0 * CW + j];
                    uint32 u1 = hb[(size_t)s1 * CW + j];
                    uint32 u2 = hb[(size_t)s2 * CW + j];
                    uint32 u3 = hb[(size_t)s3 * CW + j];
                    l0 = fmaxf(l0, b2f_lo(u0)); h0 = fmaxf(h0, b2f_hi(u0));
                    l1 = fmaxf(l1, b2f_lo(u1)); h1 = fmaxf(h1, b2f_hi(u1));
                    l2 = fmaxf(l2, b2f_lo(u2)); h2 = fmaxf(h2, b2f_hi(u2));
                    l3 = fmaxf(l3, b2f_lo(u3)); h3 = fmaxf(h3, b2f_hi(u3));
                }
            }
            if (ac) {
                if (i < end) {
                    uint32 u = hb[(size_t)csr_src[i] * CW + j];
                    l0 = fmaxf(l0, b2f_lo(u)); h0 = fmaxf(h0, b2f_hi(u));
                }
                if (i + 2 < end) {
                    uint32 u = hb[(size_t)csr_src[i + 2] * CW + j];
                    l1 = fmaxf(l1, b2f_lo(u)); h1 = fmaxf(h1, b2f_hi(u));
                }
                if (i + 4 < end) {
                    uint32 u = hb[(size_t)csr_src[i + 4] * CW + j];
                    l2 = fmaxf(l2, b2f_lo(u)); h2 = fmaxf(h2, b2f_hi(u));
                }
            }
            float lo = fmaxf(fmaxf(l0, l1), fmaxf(l2, l3));
            float hi = fmaxf(fmaxf(h0, h1), fmaxf(h2, h3));
            lo = fmaxf(lo, __shfl_xor(lo, 32));       // combine edge halves
            hi = fmaxf(hi, __shfl_xor(hi, 32));
            lo = (lo == NEG) ? 0.0f : lo;             // empty segment -> 0
            hi = (hi == NEG) ? 0.0f : hi;
            if (p == 0 && ac) {
                sAgg[g][2 * j]     = lo;
                sAgg[g][2 * j + 1] = hi;
            } else if (p == 1 && ac) {
                uint32 u = hb[(size_t)n * CW + j];    // own row
                sH[g][2 * j]     = b2f_lo(u);
                sH[g][2 * j + 1] = b2f_hi(u);
            }
        }
        // no barrier: same-wave LDS write -> read (compiler orders via lgkmcnt)

        if (n < NN) {
            const int KH = DIN / 2;                  // 25 or 16
            const int k0 = p * KH;
            const int k1 = (p == 1) ? DIN : KH;
            float part = (p == 0) ? sb[j] : 0.0f;
#pragma unroll
            for (int k = k0; k < k1; ++k) {
                part += sAgg[g][k] * sWl[k * CD + j] + sH[g][k] * sWr[k * CD + j];
            }
            float acc = part + __shfl_xor(part, 32);
            if (lane < 32) {
                if (MODE == 0) {
                    acc = fmaxf(acc, 0.0f);
                    ((ushort16*)out_v)[(size_t)n * CD + j] = f2b(acc);
                } else {
                    float m = acc;
                    for (int off = 16; off > 0; off >>= 1) m = fmaxf(m, __shfl_xor(m, off, 32));
                    float ex = expf(acc - m);
                    float s = ex;
                    for (int off = 16; off > 0; off >>= 1) s += __shfl_xor(s, off, 32);
                    acc = acc - m - logf(s);
                    ((float*)out_v)[(size_t)n * CD + j] = acc;
                }
            }
        }
    }
}

// ---------------------------------------------------------------------------
extern "C" void kernel_launch(void* const* d_in, const int* in_sizes, int n_in,
                              void* d_out, int out_size, void* d_ws, size_t ws_size,
                              hipStream_t stream) {
    const float* x    = (const float*)d_in[0];
    const void*  edge = d_in[1];
    const float* Wl1 = (const float*)d_in[2];
    const float* bl1 = (const float*)d_in[3];
    const float* Wr1 = (const float*)d_in[4];
    const float* Wl2 = (const float*)d_in[5];
    const float* bl2 = (const float*)d_in[6];
    const float* Wr2 = (const float*)d_in[7];
    const float* Wl3 = (const float*)d_in[8];
    const float* bl3 = (const float*)d_in[9];
    const float* Wr3 = (const float*)d_in[10];

    const int E = in_sizes[1] / 2;

    // Workspace carve-up (256B aligned). Total ≈ 30.2 MB.
    char* ws = (char*)d_ws;
    size_t off = 0;
    auto carve = [&](size_t bytes) {
        void* p = ws + off;
        off = (off + bytes + 255) & ~(size_t)255;
        return p;
    };
    int*    counts    = (int*)   carve((size_t)NN * 4);     // aliased as cursor
    int*    cursor    = counts;
    int*    offsets   = (int*)   carve((size_t)(NN + 1) * 4);
    int*    flag      = (int*)   carve(4);
    int*    blockSums = (int*)   carve((size_t)SCAN_NB * 4);
    int*    csr_src   = (int*)   carve((size_t)E * 4);
    uint32* xb        = (uint32*)carve((size_t)NN * 25 * 4);  // x in bf16 (10 MB)
    uint32* h1b       = (uint32*)carve((size_t)NN * 16 * 4);  // h1 bf16 (6.4 MB)
    uint32* h2b       = (uint32*)carve((size_t)NN * 16 * 4);  // h2 bf16 (6.4 MB)
    float*  out       = (float*)d_out;
    (void)ws_size; (void)n_in; (void)out_size;

    hipMemsetAsync(counts, 0, (size_t)NN * 4, stream);
    detect_idx64<<<1, 64, 0, stream>>>(edge, flag);

    const int NQ = NN * 50 / 4;
    cvt_x_kernel<<<(NQ + 255) / 256, 256, 0, stream>>>(x, xb);

    const int eb1 = (E + 255) / 256;
    const int eb4 = (E + 1023) / 1024;
    hist_kernel<<<eb1, 256, 0, stream>>>(edge, E, flag, counts);
    scan_partial_kernel<<<SCAN_NB, 256, 0, stream>>>(counts, blockSums);
    scan_bases_kernel<<<1, 256, 0, stream>>>(blockSums);
    scan_final_kernel<<<SCAN_NB, 256, 0, stream>>>(counts, blockSums, offsets, cursor);
    fill_kernel<<<eb4, 256, 0, stream>>>(edge, E, flag, cursor, csr_src);

    sage_layer_kernel<50, 0><<<LGRID, 256, 0, stream>>>(xb,  offsets, csr_src, Wl1, bl1, Wr1, h1b);
    sage_layer_kernel<32, 0><<<LGRID, 256, 0, stream>>>(h1b, offsets, csr_src, Wl2, bl2, Wr2, h2b);
    sage_layer_kernel<32, 2><<<LGRID, 256, 0, stream>>>(h2b, offsets, csr_src, Wl3, bl3, Wr3, out);
}